// Round 2
// baseline (1351.153 us; speedup 1.0000x reference)
//
#include <hip/hip_runtime.h>
#include <hip/hip_bf16.h>

#define NPK   1280000   // B*N*K
#define NPTS  80000     // B*N
#define NK    640000    // N*K
#define NPN   40000     // N
#define CHUNK 16000     // points per chunk (must divide NPTS, divisible by 64)
#define NCHUNK 5

// stats layout in ws (floats):
// [0,64)    pe_sum    [64,128)  pe_sq
// [128,136) h1_sum    [136,144) h1_sq
// [144,152) h2_sum    [152,160) h2_sq
// [160,176) h3_sum    [176,192) h3_sq
// [192,320) lin_sum   [320,448) lin_sq

__device__ inline float wred(float v){
  #pragma unroll
  for (int m = 32; m; m >>= 1) v += __shfl_xor(v, m, 64);
  return v;
}

// ---------------- K1: VI transform -> out2 (weightNetInput), h1 pre-act stats
__global__ __launch_bounds__(256) void k_vi(const float* __restrict__ xyz,
                                            const float* __restrict__ nrm,
                                            const int*   __restrict__ nei,
                                            const float* __restrict__ w1,
                                            const float* __restrict__ b1,
                                            float* __restrict__ out2,
                                            float* __restrict__ stats){
  int tid = threadIdx.x;
  float s[8] = {0,0,0,0,0,0,0,0}, q[8] = {0,0,0,0,0,0,0,0};
  #pragma unroll 1
  for (int it = 0; it < 8; ++it){
    int g = blockIdx.x*256 + tid + it*160000;       // 625*256*8 == NPK exactly
    int b  = g / NK;
    int nk = g - b*NK;
    int n  = nk >> 4;
    int pr = (b*NPN + n)*3;
    int jr = (b*NPN + nei[g])*3;
    float cx = xyz[pr],   cy = xyz[pr+1], cz = xyz[pr+2];
    float nx = nrm[pr],   ny = nrm[pr+1], nz = nrm[pr+2];
    float lx = xyz[jr]-cx, ly = xyz[jr+1]-cy, lz = xyz[jr+2]-cz;
    float gx = nrm[jr],   gy = nrm[jr+1], gz = nrm[jr+2];
    float t9 = sqrtf(lx*lx + ly*ly + lz*lz);
    float ir = 1.0f / fmaxf(t9, 1e-12f);
    float rx = lx*ir, ry = ly*ir, rz = lz*ir;
    float t2 = nx*rx + ny*ry + nz*rz;               // proj
    float vx = nx - t2*rx, vy = ny - t2*ry, vz = nz - t2*rz;
    float vn = sqrtf(vx*vx + vy*vy + vz*vz);
    float iv = 1.0f / fmaxf(vn, 1e-12f);
    vx *= iv; vy *= iv; vz *= iv;
    float wx = ry*vz - rz*vy, wy = rz*vx - rx*vz, wz = rx*vy - ry*vx;
    float wn = sqrtf(wx*wx + wy*wy + wz*wz);
    float iw = 1.0f / fmaxf(wn, 1e-12f);
    wx *= iw; wy *= iw; wz *= iw;
    float t1 = gx*nx + gy*ny + gz*nz;
    float t3 = rx*gx + ry*gy + rz*gz;
    float t4 = lx*nx + ly*ny + lz*nz;
    float t6 = gx*vx + gy*vy + gz*vz;
    float t7 = gx*wx + gy*wy + gz*wz;
    float ccx = gy*nz - gz*ny, ccy = gz*nx - gx*nz, ccz = gx*ny - gy*nx;
    float t8 = lx*ccx + ly*ccy + lz*ccz;
    float wni[12] = {t1,t2,t3,t4,t3,t6,t7,t8,t9,lx,ly,lz};   // t5 == t3
    float4* o = (float4*)(out2 + (size_t)g*12);
    o[0] = make_float4(t1,t2,t3,t4);
    o[1] = make_float4(t3,t6,t7,t8);
    o[2] = make_float4(t9,lx,ly,lz);
    #pragma unroll
    for (int jj = 0; jj < 8; ++jj){
      float a = b1[jj];
      #pragma unroll
      for (int i = 0; i < 12; ++i) a = fmaf(wni[i], w1[i*8 + jj], a);
      s[jj] += a; q[jj] += a*a;
    }
  }
  __shared__ float red[4][16];
  int lane = tid & 63, wv = tid >> 6;
  float st[16];
  #pragma unroll
  for (int i = 0; i < 8; ++i){ st[i] = s[i]; st[8+i] = q[i]; }
  #pragma unroll
  for (int i = 0; i < 16; ++i) st[i] = wred(st[i]);
  if (lane == 0){
    #pragma unroll
    for (int i = 0; i < 16; ++i) red[wv][i] = st[i];
  }
  __syncthreads();
  if (tid < 16)
    atomicAdd(&stats[128 + tid], red[0][tid] + red[1][tid] + red[2][tid] + red[3][tid]);
}

// ---------------- K2: pe pre-activation stats only (no X materialization)
__global__ __launch_bounds__(256) void k_pe_stats(const float* __restrict__ feats,
                                                  const int*   __restrict__ nei,
                                                  const float* __restrict__ out2,
                                                  const float* __restrict__ w_pe,
                                                  const float* __restrict__ b_pe,
                                                  float* __restrict__ stats){
  __shared__ float a_tile[4][4][80];
  int tid = threadIdx.x, w = tid >> 6, lane = tid & 63;
  int l16 = lane & 15, tloc = lane >> 4;
  float wpe[76];
  #pragma unroll
  for (int i = 0; i < 76; ++i) wpe[i] = w_pe[i*64 + lane];
  float bpe = b_pe[lane];
  float ps = 0.f, pq = 0.f;
  for (int grp = blockIdx.x*4 + w; grp < 320000; grp += gridDim.x*4){
    {  // stage 4 points (each 16-lane subgroup stages one) -- same-wave lockstep
      int pk  = grp*4 + tloc;
      int b   = pk / NK;
      int row = b*NPN + nei[pk];
      const float* fr = feats + (size_t)row*64;
      float* at = a_tile[w][tloc];
      at[l16]      = fr[l16];
      at[l16+16]   = fr[l16+16];
      at[l16+32]   = fr[l16+32];
      at[l16+48]   = fr[l16+48];
      if (l16 < 12) at[64+l16] = out2[(size_t)pk*12 + l16];
    }
    __builtin_amdgcn_sched_barrier(0);   // keep ds_reads after ds_writes
    #pragma unroll
    for (int t = 0; t < 4; ++t){
      const float4* ar = (const float4*)&a_tile[w][t][0];
      float acc = bpe;
      #pragma unroll
      for (int i = 0; i < 19; ++i){
        float4 a4 = ar[i];
        acc = fmaf(a4.x, wpe[4*i+0], acc);
        acc = fmaf(a4.y, wpe[4*i+1], acc);
        acc = fmaf(a4.z, wpe[4*i+2], acc);
        acc = fmaf(a4.w, wpe[4*i+3], acc);
      }
      ps += acc; pq += acc*acc;
    }
  }
  __syncthreads();
  float* r = &a_tile[0][0][0];
  r[tid] = ps; __syncthreads();
  if (tid < 64) atomicAdd(&stats[tid],      r[tid] + r[tid+64] + r[tid+128] + r[tid+192]);
  __syncthreads();
  r[tid] = pq; __syncthreads();
  if (tid < 64) atomicAdd(&stats[64 + tid], r[tid] + r[tid+64] + r[tid+128] + r[tid+192]);
}

// ---------------- K3a: h2 pre-act stats
__global__ __launch_bounds__(256) void k3a(const float* __restrict__ out2,
                                           const float* __restrict__ w1, const float* __restrict__ b1,
                                           const float* __restrict__ w2, const float* __restrict__ b2,
                                           float* __restrict__ stats){
  int tid = threadIdx.x;
  const float invc = 1.0f/1280000.0f;
  float sc1[8], sh1[8];
  #pragma unroll
  for (int j = 0; j < 8; ++j){
    float m = stats[128+j]*invc, v = stats[136+j]*invc - m*m;
    float c = rsqrtf(fmaxf(v, 0.f) + 1e-5f); sc1[j] = c; sh1[j] = -m*c;
  }
  float s[8] = {0,0,0,0,0,0,0,0}, q[8] = {0,0,0,0,0,0,0,0};
  #pragma unroll 1
  for (int it = 0; it < 8; ++it){
    int g = blockIdx.x*256 + tid + it*160000;
    const float4* wp = (const float4*)(out2 + (size_t)g*12);
    float4 a0 = wp[0], a1 = wp[1], a2 = wp[2];
    float wni[12] = {a0.x,a0.y,a0.z,a0.w,a1.x,a1.y,a1.z,a1.w,a2.x,a2.y,a2.z,a2.w};
    float h1[8];
    #pragma unroll
    for (int j = 0; j < 8; ++j){
      float a = b1[j];
      #pragma unroll
      for (int i = 0; i < 12; ++i) a = fmaf(wni[i], w1[i*8+j], a);
      h1[j] = fmaxf(fmaf(a, sc1[j], sh1[j]), 0.f);
    }
    #pragma unroll
    for (int j = 0; j < 8; ++j){
      float a = b2[j];
      #pragma unroll
      for (int i = 0; i < 8; ++i) a = fmaf(h1[i], w2[i*8+j], a);
      s[j] += a; q[j] += a*a;
    }
  }
  __shared__ float red[4][16];
  int lane = tid & 63, wv = tid >> 6;
  float st[16];
  #pragma unroll
  for (int i = 0; i < 8; ++i){ st[i] = s[i]; st[8+i] = q[i]; }
  #pragma unroll
  for (int i = 0; i < 16; ++i) st[i] = wred(st[i]);
  if (lane == 0){
    #pragma unroll
    for (int i = 0; i < 16; ++i) red[wv][i] = st[i];
  }
  __syncthreads();
  if (tid < 16)
    atomicAdd(&stats[144 + tid], red[0][tid] + red[1][tid] + red[2][tid] + red[3][tid]);
}

// ---------------- K3b: h3 pre-act stats
__global__ __launch_bounds__(256) void k3b(const float* __restrict__ out2,
                                           const float* __restrict__ w1, const float* __restrict__ b1,
                                           const float* __restrict__ w2, const float* __restrict__ b2,
                                           const float* __restrict__ w3, const float* __restrict__ b3,
                                           float* __restrict__ stats){
  int tid = threadIdx.x;
  const float invc = 1.0f/1280000.0f;
  float sc1[8], sh1[8], sc2[8], sh2[8];
  #pragma unroll
  for (int j = 0; j < 8; ++j){
    float m = stats[128+j]*invc, v = stats[136+j]*invc - m*m;
    float c = rsqrtf(fmaxf(v, 0.f) + 1e-5f); sc1[j] = c; sh1[j] = -m*c;
    m = stats[144+j]*invc; v = stats[152+j]*invc - m*m;
    c = rsqrtf(fmaxf(v, 0.f) + 1e-5f); sc2[j] = c; sh2[j] = -m*c;
  }
  float s[16], q[16];
  #pragma unroll
  for (int j = 0; j < 16; ++j){ s[j] = 0.f; q[j] = 0.f; }
  #pragma unroll 1
  for (int it = 0; it < 8; ++it){
    int g = blockIdx.x*256 + tid + it*160000;
    const float4* wp = (const float4*)(out2 + (size_t)g*12);
    float4 a0 = wp[0], a1 = wp[1], a2 = wp[2];
    float wni[12] = {a0.x,a0.y,a0.z,a0.w,a1.x,a1.y,a1.z,a1.w,a2.x,a2.y,a2.z,a2.w};
    float h1[8], h2[8];
    #pragma unroll
    for (int j = 0; j < 8; ++j){
      float a = b1[j];
      #pragma unroll
      for (int i = 0; i < 12; ++i) a = fmaf(wni[i], w1[i*8+j], a);
      h1[j] = fmaxf(fmaf(a, sc1[j], sh1[j]), 0.f);
    }
    #pragma unroll
    for (int j = 0; j < 8; ++j){
      float a = b2[j];
      #pragma unroll
      for (int i = 0; i < 8; ++i) a = fmaf(h1[i], w2[i*8+j], a);
      h2[j] = fmaxf(fmaf(a, sc2[j], sh2[j]), 0.f);
    }
    #pragma unroll
    for (int j = 0; j < 16; ++j){
      float a = b3[j];
      #pragma unroll
      for (int i = 0; i < 8; ++i) a = fmaf(h2[i], w3[i*16+j], a);
      s[j] += a; q[j] += a*a;
    }
  }
  __shared__ float red[4][32];
  int lane = tid & 63, wv = tid >> 6;
  float st[32];
  #pragma unroll
  for (int i = 0; i < 16; ++i){ st[i] = s[i]; st[16+i] = q[i]; }
  #pragma unroll
  for (int i = 0; i < 32; ++i) st[i] = wred(st[i]);
  if (lane == 0){
    #pragma unroll
    for (int i = 0; i < 32; ++i) red[wv][i] = st[i];
  }
  __syncthreads();
  if (tid < 32)
    atomicAdd(&stats[160 + tid], red[0][tid] + red[1][tid] + red[2][tid] + red[3][tid]);
}

// ---------------- K3c: full MLP chain -> WG chunk (CHUNK pts x 16k x 16w)
__global__ __launch_bounds__(256) void k3c(const float* __restrict__ out2,
                                           const float* __restrict__ w1, const float* __restrict__ b1,
                                           const float* __restrict__ w2, const float* __restrict__ b2,
                                           const float* __restrict__ w3, const float* __restrict__ b3,
                                           const float* __restrict__ stats,
                                           float* __restrict__ WG, int c0){
  int idx = blockIdx.x*256 + threadIdx.x;        // [0, CHUNK*16)
  const float invc = 1.0f/1280000.0f;
  float sc1[8], sh1[8], sc2[8], sh2[8], sc3[16], sh3[16];
  #pragma unroll
  for (int j = 0; j < 8; ++j){
    float m = stats[128+j]*invc, v = stats[136+j]*invc - m*m;
    float c = rsqrtf(fmaxf(v, 0.f) + 1e-5f); sc1[j] = c; sh1[j] = -m*c;
    m = stats[144+j]*invc; v = stats[152+j]*invc - m*m;
    c = rsqrtf(fmaxf(v, 0.f) + 1e-5f); sc2[j] = c; sh2[j] = -m*c;
  }
  #pragma unroll
  for (int j = 0; j < 16; ++j){
    float m = stats[160+j]*invc, v = stats[176+j]*invc - m*m;
    float c = rsqrtf(fmaxf(v, 0.f) + 1e-5f); sc3[j] = c; sh3[j] = -m*c;
  }
  size_t g = (size_t)c0*16 + idx;
  const float4* wp = (const float4*)(out2 + g*12);
  float4 a0 = wp[0], a1 = wp[1], a2 = wp[2];
  float wni[12] = {a0.x,a0.y,a0.z,a0.w,a1.x,a1.y,a1.z,a1.w,a2.x,a2.y,a2.z,a2.w};
  float h1[8], h2[8], h3[16];
  #pragma unroll
  for (int j = 0; j < 8; ++j){
    float a = b1[j];
    #pragma unroll
    for (int i = 0; i < 12; ++i) a = fmaf(wni[i], w1[i*8+j], a);
    h1[j] = fmaxf(fmaf(a, sc1[j], sh1[j]), 0.f);
  }
  #pragma unroll
  for (int j = 0; j < 8; ++j){
    float a = b2[j];
    #pragma unroll
    for (int i = 0; i < 8; ++i) a = fmaf(h1[i], w2[i*8+j], a);
    h2[j] = fmaxf(fmaf(a, sc2[j], sh2[j]), 0.f);
  }
  #pragma unroll
  for (int j = 0; j < 16; ++j){
    float a = b3[j];
    #pragma unroll
    for (int i = 0; i < 8; ++i) a = fmaf(h2[i], w3[i*16+j], a);
    h3[j] = fmaxf(fmaf(a, sc3[j], sh3[j]), 0.f);
  }
  float4* o = (float4*)(WG + (size_t)idx*16);
  o[0] = make_float4(h3[0], h3[1], h3[2], h3[3]);
  o[1] = make_float4(h3[4], h3[5], h3[6], h3[7]);
  o[2] = make_float4(h3[8], h3[9], h3[10],h3[11]);
  o[3] = make_float4(h3[12],h3[13],h3[14],h3[15]);
}

// ---------------- K4a: recompute pe (gather + GEMM + BN + relu), einsum -> M chunk
// wave = one point; lane = pe channel c. M[p_local][c*16+w] = sum_k pe(k,c)*wgt(k,w)
__global__ __launch_bounds__(256) void k4a(const float* __restrict__ feats,
                                           const int*   __restrict__ nei,
                                           const float* __restrict__ out2,
                                           const float* __restrict__ w_pe,
                                           const float* __restrict__ b_pe,
                                           const float* __restrict__ WG,
                                           const float* __restrict__ stats,
                                           float* __restrict__ M, int c0){
  __shared__ float at[4][16][80];   // [wave][k][76 pad 80] gathered A-rows
  __shared__ float4 wt[4][64];      // [wave][k*4+t] wgt row chunks
  int tid = threadIdx.x, w = tid >> 6, lane = tid & 63;
  const float invc = 1.0f/1280000.0f;
  float s  = stats[lane]*invc, q = stats[64+lane]*invc;
  float sc = rsqrtf(fmaxf(q - s*s, 0.f) + 1e-5f);
  float sh = -s*sc;
  float wpe[76];
  #pragma unroll
  for (int i = 0; i < 76; ++i) wpe[i] = w_pe[i*64 + lane];
  float bpe = b_pe[lane];

  int p_local = blockIdx.x*4 + w;          // [0, CHUNK)
  int p = c0 + p_local;
  int b = p / NPN;
  int nv = nei[p*16 + (lane & 15)];
  #pragma unroll
  for (int k = 0; k < 16; ++k){
    int row = b*NPN + __shfl(nv, k, 64);
    at[w][k][lane] = feats[(size_t)row*64 + lane];
  }
  #pragma unroll
  for (int t = 0; t < 3; ++t){
    int j = t*64 + lane;                   // 0..191 = 16k * 12c
    int k = j / 12, c = j - k*12;
    if (k < 16) at[w][k][64+c] = out2[(size_t)(p*16+k)*12 + c];
  }
  wt[w][lane] = ((const float4*)WG)[(size_t)p_local*64 + lane];
  __syncthreads();                          // uniform: one barrier per block

  float m[16];
  #pragma unroll
  for (int i = 0; i < 16; ++i) m[i] = 0.f;
  #pragma unroll 4
  for (int k = 0; k < 16; ++k){
    const float4* ar = (const float4*)&at[w][k][0];
    float acc = bpe;
    #pragma unroll
    for (int i = 0; i < 19; ++i){
      float4 a4 = ar[i];
      acc = fmaf(a4.x, wpe[4*i+0], acc);
      acc = fmaf(a4.y, wpe[4*i+1], acc);
      acc = fmaf(a4.z, wpe[4*i+2], acc);
      acc = fmaf(a4.w, wpe[4*i+3], acc);
    }
    float pe = fmaxf(fmaf(acc, sc, sh), 0.f);
    float4 w0 = wt[w][k*4+0], w1v = wt[w][k*4+1], w2v = wt[w][k*4+2], w3v = wt[w][k*4+3];
    m[0]  = fmaf(pe, w0.x,  m[0]);  m[1]  = fmaf(pe, w0.y,  m[1]);
    m[2]  = fmaf(pe, w0.z,  m[2]);  m[3]  = fmaf(pe, w0.w,  m[3]);
    m[4]  = fmaf(pe, w1v.x, m[4]);  m[5]  = fmaf(pe, w1v.y, m[5]);
    m[6]  = fmaf(pe, w1v.z, m[6]);  m[7]  = fmaf(pe, w1v.w, m[7]);
    m[8]  = fmaf(pe, w2v.x, m[8]);  m[9]  = fmaf(pe, w2v.y, m[9]);
    m[10] = fmaf(pe, w2v.z, m[10]); m[11] = fmaf(pe, w2v.w, m[11]);
    m[12] = fmaf(pe, w3v.x, m[12]); m[13] = fmaf(pe, w3v.y, m[13]);
    m[14] = fmaf(pe, w3v.z, m[14]); m[15] = fmaf(pe, w3v.w, m[15]);
  }
  float4* mo = (float4*)(M + (size_t)p_local*1024 + lane*16);
  mo[0] = make_float4(m[0], m[1], m[2], m[3]);
  mo[1] = make_float4(m[4], m[5], m[6], m[7]);
  mo[2] = make_float4(m[8], m[9], m[10],m[11]);
  mo[3] = make_float4(m[12],m[13],m[14],m[15]);
}

// ---------------- K4b: GEMM  (CHUNK x 1024) @ (1024 x 128) + b_lin -> LP chunk
__global__ __launch_bounds__(256) void k4b(const float* __restrict__ A,
                                           const float* __restrict__ Bw,
                                           const float* __restrict__ bl,
                                           float* __restrict__ LP, int c0){
  __shared__ float  As[32][68];
  __shared__ float4 Bs[32][32];
  int tid = threadIdx.x;
  int pb  = blockIdx.x * 64;               // local row base
  int tm  = tid >> 5, tn = tid & 31;
  float acc[8][4];
  #pragma unroll
  for (int i = 0; i < 8; ++i)
    #pragma unroll
    for (int j = 0; j < 4; ++j) acc[i][j] = 0.f;

  for (int k0 = 0; k0 < 1024; k0 += 32){
    #pragma unroll
    for (int e = 0; e < 8; ++e){
      int idx = tid + e*256; int mi = idx >> 5, ki = idx & 31;
      As[ki][mi] = A[(size_t)(pb + mi)*1024 + k0 + ki];
    }
    #pragma unroll
    for (int e = 0; e < 4; ++e){
      int idx = tid + e*256; int ki = idx >> 5, ni = idx & 31;
      Bs[ki][ni] = ((const float4*)Bw)[(k0 + ki)*32 + ni];
    }
    __syncthreads();
    #pragma unroll
    for (int k = 0; k < 32; ++k){
      const float4* ar = (const float4*)&As[k][0];
      float4 a0 = ar[tm*2], a1 = ar[tm*2 + 1];
      float4 b  = Bs[k][tn];
      float av[8] = {a0.x,a0.y,a0.z,a0.w,a1.x,a1.y,a1.z,a1.w};
      #pragma unroll
      for (int i = 0; i < 8; ++i){
        acc[i][0] = fmaf(av[i], b.x, acc[i][0]);
        acc[i][1] = fmaf(av[i], b.y, acc[i][1]);
        acc[i][2] = fmaf(av[i], b.z, acc[i][2]);
        acc[i][3] = fmaf(av[i], b.w, acc[i][3]);
      }
    }
    __syncthreads();
  }
  float4 blv = ((const float4*)bl)[tn];
  #pragma unroll
  for (int i = 0; i < 8; ++i){
    int p = c0 + pb + tm*8 + i;
    float4 o = make_float4(acc[i][0] + blv.x, acc[i][1] + blv.y,
                           acc[i][2] + blv.z, acc[i][3] + blv.w);
    ((float4*)(LP + (size_t)p*128))[tn] = o;
  }
}

// ---------------- K4c: lin pre-act stats
__global__ __launch_bounds__(256) void k4c(const float* __restrict__ LP,
                                           float* __restrict__ stats){
  int tid = threadIdx.x; int ch = tid & 127; int half = tid >> 7;
  float s = 0.f, q = 0.f;
  for (int p = blockIdx.x*2 + half; p < NPTS; p += gridDim.x*2){
    float v = LP[(size_t)p*128 + ch]; s += v; q += v*v;
  }
  __shared__ float r[256];
  r[tid] = s; __syncthreads();
  if (tid < 128) atomicAdd(&stats[192 + tid], r[tid] + r[tid+128]);
  __syncthreads();
  r[tid] = q; __syncthreads();
  if (tid < 128) atomicAdd(&stats[320 + tid], r[tid] + r[tid+128]);
}

// ---------------- K5: apply lin BN + relu (in-place over LP region == out1)
__global__ __launch_bounds__(256) void k5(float* __restrict__ LP,
                                          const float* __restrict__ stats){
  __shared__ float sc[128], sh[128];
  int tid = threadIdx.x;
  if (tid < 128){
    const float invc = 1.0f/80000.0f;
    float s = stats[192+tid]*invc, q = stats[320+tid]*invc;
    float c = rsqrtf(fmaxf(q - s*s, 0.f) + 1e-5f);
    sc[tid] = c; sh[tid] = -s*c;
  }
  __syncthreads();
  for (int g4 = blockIdx.x*256 + tid; g4 < 2560000; g4 += gridDim.x*256){
    int cb = (g4 & 31) * 4;
    float4 v = ((const float4*)LP)[g4];
    float4 o;
    o.x = fmaxf(fmaf(v.x, sc[cb+0], sh[cb+0]), 0.f);
    o.y = fmaxf(fmaf(v.y, sc[cb+1], sh[cb+1]), 0.f);
    o.z = fmaxf(fmaf(v.z, sc[cb+2], sh[cb+2]), 0.f);
    o.w = fmaxf(fmaf(v.w, sc[cb+3], sh[cb+3]), 0.f);
    ((float4*)LP)[g4] = o;
  }
}

extern "C" void kernel_launch(void* const* d_in, const int* in_sizes, int n_in,
                              void* d_out, int out_size, void* d_ws, size_t ws_size,
                              hipStream_t stream){
  const float* xyz   = (const float*)d_in[0];
  const float* feats = (const float*)d_in[1];
  const float* nrm   = (const float*)d_in[2];
  const int*   nei   = (const int*)  d_in[3];
  const float* w_pe  = (const float*)d_in[4];
  const float* b_pe  = (const float*)d_in[5];
  const float* w1    = (const float*)d_in[6];
  const float* b1    = (const float*)d_in[7];
  const float* w2    = (const float*)d_in[8];
  const float* b2    = (const float*)d_in[9];
  const float* w3    = (const float*)d_in[10];
  const float* b3    = (const float*)d_in[11];
  const float* wl    = (const float*)d_in[12];
  const float* blin  = (const float*)d_in[13];

  float* out1 = (float*)d_out;             // new_feat (B,N,128) = 10,240,000 f; doubles as LP scratch
  float* out2 = out1 + 10240000;           // weightNetInput (B,N,K,12) = 15,360,000 f

  // ws: stats 512 f | WG CHUNK*256 f (16.4 MB) | M CHUNK*1024 f (65.5 MB)  => ~82 MB total
  float* stats = (float*)d_ws;
  float* WG    = stats + 512;
  float* M     = WG + (size_t)CHUNK*256;

  hipMemsetAsync(stats, 0, 512*sizeof(float), stream);
  k_vi      <<<625, 256, 0, stream>>>(xyz, nrm, nei, w1, b1, out2, stats);
  k_pe_stats<<<1280, 256, 0, stream>>>(feats, nei, out2, w_pe, b_pe, stats);
  k3a       <<<625, 256, 0, stream>>>(out2, w1, b1, w2, b2, stats);
  k3b       <<<625, 256, 0, stream>>>(out2, w1, b1, w2, b2, w3, b3, stats);
  for (int c = 0; c < NCHUNK; ++c){
    int c0 = c * CHUNK;
    k3c<<<CHUNK*16/256, 256, 0, stream>>>(out2, w1, b1, w2, b2, w3, b3, stats, WG, c0);
    k4a<<<CHUNK/4,      256, 0, stream>>>(feats, nei, out2, w_pe, b_pe, WG, stats, M, c0);
    k4b<<<CHUNK/64,     256, 0, stream>>>(M, wl, blin, out1, c0);
  }
  k4c<<<512, 256, 0, stream>>>(out1, stats);
  k5 <<<1280, 256, 0, stream>>>(out1, stats);
}

// Round 6
// 945.310 us; speedup vs baseline: 1.4293x; 1.4293x over previous
//
#include <hip/hip_runtime.h>
#include <hip/hip_bf16.h>

#define NPK   1280000   // B*N*K
#define NPTS  80000     // B*N
#define NK    640000    // N*K
#define NPN   40000     // N
#define CHUNK 8000      // points per chunk (divisible by 64)
#define NCHUNK 10

// stats layout in ws (floats):
// [0,64)    pe_sum    [64,128)  pe_sq
// [128,136) h1_sum    [136,144) h1_sq
// [144,152) h2_sum    [152,160) h2_sq
// [160,176) h3_sum    [176,192) h3_sq
// [192,320) lin_sum   [320,448) lin_sq

typedef __attribute__((ext_vector_type(8))) short bf16x8;
typedef __attribute__((ext_vector_type(4))) float f32x4;

__device__ inline unsigned short f2bf(float f){       // RNE f32->bf16
  union { float f; unsigned u; } v; v.f = f;
  unsigned r = v.u + 0x7FFFu + ((v.u >> 16) & 1u);
  return (unsigned short)(r >> 16);
}

__device__ inline float wred(float v){
  #pragma unroll
  for (int m = 32; m; m >>= 1) v += __shfl_xor(v, m, 64);
  return v;
}

// ---------------- kWT: w_lin -> transposed bf16 copy wlT[n][k]
__global__ __launch_bounds__(256) void kWT(const float* __restrict__ wl,
                                           short* __restrict__ wlT){
  int idx = blockIdx.x*256 + threadIdx.x;          // 512 blocks * 256 = 131072
  float v = wl[idx];                                // coalesced read
  int k = idx >> 7, n = idx & 127;
  wlT[(size_t)n*1024 + k] = (short)f2bf(v);         // scattered 2B write (one-time)
}

// ---------------- kF: F = feats @ w_pe[:64,:] + b_pe   (80000 x 64)
__global__ __launch_bounds__(256, 2) void kF(const float* __restrict__ feats,
                                             const float* __restrict__ w_pe,
                                             const float* __restrict__ b_pe,
                                             float* __restrict__ F){
  __shared__ float af[4][64];
  int tid = threadIdx.x, w = tid >> 6, lane = tid & 63;
  float wf[64];
  #pragma unroll
  for (int i = 0; i < 64; ++i) wf[i] = w_pe[i*64 + lane];
  float bp = b_pe[lane];
  int wid = blockIdx.x*4 + w;
  for (int r = wid; r < NPTS; r += 2560){
    af[w][lane] = feats[(size_t)r*64 + lane];       // same-wave stage + read
    const float4* ar = (const float4*)&af[w][0];
    float acc = bp;
    #pragma unroll
    for (int i = 0; i < 16; ++i){
      float4 a4 = ar[i];
      acc = fmaf(a4.x, wf[4*i+0], acc);
      acc = fmaf(a4.y, wf[4*i+1], acc);
      acc = fmaf(a4.z, wf[4*i+2], acc);
      acc = fmaf(a4.w, wf[4*i+3], acc);
    }
    F[(size_t)r*64 + lane] = acc;
  }
}

// ---------------- K1: VI transform -> out2 (weightNetInput), h1 pre-act stats
__global__ __launch_bounds__(256) void k_vi(const float* __restrict__ xyz,
                                            const float* __restrict__ nrm,
                                            const int*   __restrict__ nei,
                                            const float* __restrict__ w1,
                                            const float* __restrict__ b1,
                                            float* __restrict__ out2,
                                            float* __restrict__ stats){
  int tid = threadIdx.x;
  float s[8] = {0,0,0,0,0,0,0,0}, q[8] = {0,0,0,0,0,0,0,0};
  #pragma unroll 1
  for (int it = 0; it < 8; ++it){
    int g = blockIdx.x*256 + tid + it*160000;       // 625*256*8 == NPK exactly
    int b  = g / NK;
    int nk = g - b*NK;
    int n  = nk >> 4;
    int pr = (b*NPN + n)*3;
    int jr = (b*NPN + nei[g])*3;
    float cx = xyz[pr],   cy = xyz[pr+1], cz = xyz[pr+2];
    float nx = nrm[pr],   ny = nrm[pr+1], nz = nrm[pr+2];
    float lx = xyz[jr]-cx, ly = xyz[jr+1]-cy, lz = xyz[jr+2]-cz;
    float gx = nrm[jr],   gy = nrm[jr+1], gz = nrm[jr+2];
    float t9 = sqrtf(lx*lx + ly*ly + lz*lz);
    float ir = 1.0f / fmaxf(t9, 1e-12f);
    float rx = lx*ir, ry = ly*ir, rz = lz*ir;
    float t2 = nx*rx + ny*ry + nz*rz;               // proj
    float vx = nx - t2*rx, vy = ny - t2*ry, vz = nz - t2*rz;
    float vn = sqrtf(vx*vx + vy*vy + vz*vz);
    float iv = 1.0f / fmaxf(vn, 1e-12f);
    vx *= iv; vy *= iv; vz *= iv;
    float wx = ry*vz - rz*vy, wy = rz*vx - rx*vz, wz = rx*vy - ry*vx;
    float wn = sqrtf(wx*wx + wy*wy + wz*wz);
    float iw = 1.0f / fmaxf(wn, 1e-12f);
    wx *= iw; wy *= iw; wz *= iw;
    float t1 = gx*nx + gy*ny + gz*nz;
    float t3 = rx*gx + ry*gy + rz*gz;
    float t4 = lx*nx + ly*ny + lz*nz;
    float t6 = gx*vx + gy*vy + gz*vz;
    float t7 = gx*wx + gy*wy + gz*wz;
    float ccx = gy*nz - gz*ny, ccy = gz*nx - gx*nz, ccz = gx*ny - gy*nx;
    float t8 = lx*ccx + ly*ccy + lz*ccz;
    float wni[12] = {t1,t2,t3,t4,t3,t6,t7,t8,t9,lx,ly,lz};   // t5 == t3
    float4* o = (float4*)(out2 + (size_t)g*12);
    o[0] = make_float4(t1,t2,t3,t4);
    o[1] = make_float4(t3,t6,t7,t8);
    o[2] = make_float4(t9,lx,ly,lz);
    #pragma unroll
    for (int jj = 0; jj < 8; ++jj){
      float a = b1[jj];
      #pragma unroll
      for (int i = 0; i < 12; ++i) a = fmaf(wni[i], w1[i*8 + jj], a);
      s[jj] += a; q[jj] += a*a;
    }
  }
  __shared__ float red[4][16];
  int lane = tid & 63, wv = tid >> 6;
  float st[16];
  #pragma unroll
  for (int i = 0; i < 8; ++i){ st[i] = s[i]; st[8+i] = q[i]; }
  #pragma unroll
  for (int i = 0; i < 16; ++i) st[i] = wred(st[i]);
  if (lane == 0){
    #pragma unroll
    for (int i = 0; i < 16; ++i) red[wv][i] = st[i];
  }
  __syncthreads();
  if (tid < 16)
    atomicAdd(&stats[128 + tid], red[0][tid] + red[1][tid] + red[2][tid] + red[3][tid]);
}

// ---------------- K2: pe pre-act stats via F-gather (lane = channel)
__global__ __launch_bounds__(256) void k_pe2(const float* __restrict__ F,
                                             const int*   __restrict__ nei,
                                             const float* __restrict__ out2,
                                             const float* __restrict__ w_pe,
                                             float* __restrict__ stats){
  int tid = threadIdx.x, lane = tid & 63;
  float gw[12];
  #pragma unroll
  for (int i = 0; i < 12; ++i) gw[i] = w_pe[(64+i)*64 + lane];
  float s = 0.f, q = 0.f;
  int wid = blockIdx.x*4 + (tid >> 6);
  #pragma unroll 2
  for (int pk = wid; pk < NPK; pk += 5120){
    int row = (pk >= NK ? NPN : 0) + nei[pk];
    float xv = F[(size_t)row*64 + lane];            // coalesced 256B gather
    const float4* wp = (const float4*)(out2 + (size_t)pk*12);
    float4 u0 = wp[0], u1 = wp[1], u2 = wp[2];      // wave-uniform broadcast
    float g = u0.x*gw[0];
    g = fmaf(u0.y, gw[1],  g); g = fmaf(u0.z, gw[2],  g); g = fmaf(u0.w, gw[3],  g);
    g = fmaf(u1.x, gw[4],  g); g = fmaf(u1.y, gw[5],  g); g = fmaf(u1.z, gw[6],  g);
    g = fmaf(u1.w, gw[7],  g); g = fmaf(u2.x, gw[8],  g); g = fmaf(u2.y, gw[9],  g);
    g = fmaf(u2.z, gw[10], g); g = fmaf(u2.w, gw[11], g);
    float x = xv + g;
    s += x; q += x*x;
  }
  __shared__ float r[256];
  r[tid] = s; __syncthreads();
  if (tid < 64) atomicAdd(&stats[tid],      r[tid] + r[tid+64] + r[tid+128] + r[tid+192]);
  __syncthreads();
  r[tid] = q; __syncthreads();
  if (tid < 64) atomicAdd(&stats[64 + tid], r[tid] + r[tid+64] + r[tid+128] + r[tid+192]);
}

// ---------------- K3a: h2 pre-act stats
__global__ __launch_bounds__(256) void k3a(const float* __restrict__ out2,
                                           const float* __restrict__ w1, const float* __restrict__ b1,
                                           const float* __restrict__ w2, const float* __restrict__ b2,
                                           float* __restrict__ stats){
  int tid = threadIdx.x;
  const float invc = 1.0f/1280000.0f;
  float sc1[8], sh1[8];
  #pragma unroll
  for (int j = 0; j < 8; ++j){
    float m = stats[128+j]*invc, v = stats[136+j]*invc - m*m;
    float c = rsqrtf(fmaxf(v, 0.f) + 1e-5f); sc1[j] = c; sh1[j] = -m*c;
  }
  float s[8] = {0,0,0,0,0,0,0,0}, q[8] = {0,0,0,0,0,0,0,0};
  #pragma unroll 1
  for (int it = 0; it < 8; ++it){
    int g = blockIdx.x*256 + tid + it*160000;
    const float4* wp = (const float4*)(out2 + (size_t)g*12);
    float4 a0 = wp[0], a1 = wp[1], a2 = wp[2];
    float wni[12] = {a0.x,a0.y,a0.z,a0.w,a1.x,a1.y,a1.z,a1.w,a2.x,a2.y,a2.z,a2.w};
    float h1[8];
    #pragma unroll
    for (int j = 0; j < 8; ++j){
      float a = b1[j];
      #pragma unroll
      for (int i = 0; i < 12; ++i) a = fmaf(wni[i], w1[i*8+j], a);
      h1[j] = fmaxf(fmaf(a, sc1[j], sh1[j]), 0.f);
    }
    #pragma unroll
    for (int j = 0; j < 8; ++j){
      float a = b2[j];
      #pragma unroll
      for (int i = 0; i < 8; ++i) a = fmaf(h1[i], w2[i*8+j], a);
      s[j] += a; q[j] += a*a;
    }
  }
  __shared__ float red[4][16];
  int lane = tid & 63, wv = tid >> 6;
  float st[16];
  #pragma unroll
  for (int i = 0; i < 8; ++i){ st[i] = s[i]; st[8+i] = q[i]; }
  #pragma unroll
  for (int i = 0; i < 16; ++i) st[i] = wred(st[i]);
  if (lane == 0){
    #pragma unroll
    for (int i = 0; i < 16; ++i) red[wv][i] = st[i];
  }
  __syncthreads();
  if (tid < 16)
    atomicAdd(&stats[144 + tid], red[0][tid] + red[1][tid] + red[2][tid] + red[3][tid]);
}

// ---------------- K3b: h3 pre-act stats
__global__ __launch_bounds__(256) void k3b(const float* __restrict__ out2,
                                           const float* __restrict__ w1, const float* __restrict__ b1,
                                           const float* __restrict__ w2, const float* __restrict__ b2,
                                           const float* __restrict__ w3, const float* __restrict__ b3,
                                           float* __restrict__ stats){
  int tid = threadIdx.x;
  const float invc = 1.0f/1280000.0f;
  float sc1[8], sh1[8], sc2[8], sh2[8];
  #pragma unroll
  for (int j = 0; j < 8; ++j){
    float m = stats[128+j]*invc, v = stats[136+j]*invc - m*m;
    float c = rsqrtf(fmaxf(v, 0.f) + 1e-5f); sc1[j] = c; sh1[j] = -m*c;
    m = stats[144+j]*invc; v = stats[152+j]*invc - m*m;
    c = rsqrtf(fmaxf(v, 0.f) + 1e-5f); sc2[j] = c; sh2[j] = -m*c;
  }
  float s[16], q[16];
  #pragma unroll
  for (int j = 0; j < 16; ++j){ s[j] = 0.f; q[j] = 0.f; }
  #pragma unroll 1
  for (int it = 0; it < 8; ++it){
    int g = blockIdx.x*256 + tid + it*160000;
    const float4* wp = (const float4*)(out2 + (size_t)g*12);
    float4 a0 = wp[0], a1 = wp[1], a2 = wp[2];
    float wni[12] = {a0.x,a0.y,a0.z,a0.w,a1.x,a1.y,a1.z,a1.w,a2.x,a2.y,a2.z,a2.w};
    float h1[8], h2[8];
    #pragma unroll
    for (int j = 0; j < 8; ++j){
      float a = b1[j];
      #pragma unroll
      for (int i = 0; i < 12; ++i) a = fmaf(wni[i], w1[i*8+j], a);
      h1[j] = fmaxf(fmaf(a, sc1[j], sh1[j]), 0.f);
    }
    #pragma unroll
    for (int j = 0; j < 8; ++j){
      float a = b2[j];
      #pragma unroll
      for (int i = 0; i < 8; ++i) a = fmaf(h1[i], w2[i*8+j], a);
      h2[j] = fmaxf(fmaf(a, sc2[j], sh2[j]), 0.f);
    }
    #pragma unroll
    for (int j = 0; j < 16; ++j){
      float a = b3[j];
      #pragma unroll
      for (int i = 0; i < 8; ++i) a = fmaf(h2[i], w3[i*16+j], a);
      s[j] += a; q[j] += a*a;
    }
  }
  __shared__ float red[4][32];
  int lane = tid & 63, wv = tid >> 6;
  float st[32];
  #pragma unroll
  for (int i = 0; i < 16; ++i){ st[i] = s[i]; st[16+i] = q[i]; }
  #pragma unroll
  for (int i = 0; i < 32; ++i) st[i] = wred(st[i]);
  if (lane == 0){
    #pragma unroll
    for (int i = 0; i < 32; ++i) red[wv][i] = st[i];
  }
  __syncthreads();
  if (tid < 32)
    atomicAdd(&stats[160 + tid], red[0][tid] + red[1][tid] + red[2][tid] + red[3][tid]);
}

// ---------------- K3c: full MLP chain -> WG chunk (CHUNK pts x 16k x 16w)
__global__ __launch_bounds__(256) void k3c(const float* __restrict__ out2,
                                           const float* __restrict__ w1, const float* __restrict__ b1,
                                           const float* __restrict__ w2, const float* __restrict__ b2,
                                           const float* __restrict__ w3, const float* __restrict__ b3,
                                           const float* __restrict__ stats,
                                           float* __restrict__ WG, int c0){
  int idx = blockIdx.x*256 + threadIdx.x;        // [0, CHUNK*16)
  const float invc = 1.0f/1280000.0f;
  float sc1[8], sh1[8], sc2[8], sh2[8], sc3[16], sh3[16];
  #pragma unroll
  for (int j = 0; j < 8; ++j){
    float m = stats[128+j]*invc, v = stats[136+j]*invc - m*m;
    float c = rsqrtf(fmaxf(v, 0.f) + 1e-5f); sc1[j] = c; sh1[j] = -m*c;
    m = stats[144+j]*invc; v = stats[152+j]*invc - m*m;
    c = rsqrtf(fmaxf(v, 0.f) + 1e-5f); sc2[j] = c; sh2[j] = -m*c;
  }
  #pragma unroll
  for (int j = 0; j < 16; ++j){
    float m = stats[160+j]*invc, v = stats[176+j]*invc - m*m;
    float c = rsqrtf(fmaxf(v, 0.f) + 1e-5f); sc3[j] = c; sh3[j] = -m*c;
  }
  size_t g = (size_t)c0*16 + idx;
  const float4* wp = (const float4*)(out2 + g*12);
  float4 a0 = wp[0], a1 = wp[1], a2 = wp[2];
  float wni[12] = {a0.x,a0.y,a0.z,a0.w,a1.x,a1.y,a1.z,a1.w,a2.x,a2.y,a2.z,a2.w};
  float h1[8], h2[8], h3[16];
  #pragma unroll
  for (int j = 0; j < 8; ++j){
    float a = b1[j];
    #pragma unroll
    for (int i = 0; i < 12; ++i) a = fmaf(wni[i], w1[i*8+j], a);
    h1[j] = fmaxf(fmaf(a, sc1[j], sh1[j]), 0.f);
  }
  #pragma unroll
  for (int j = 0; j < 8; ++j){
    float a = b2[j];
    #pragma unroll
    for (int i = 0; i < 8; ++i) a = fmaf(h1[i], w2[i*8+j], a);
    h2[j] = fmaxf(fmaf(a, sc2[j], sh2[j]), 0.f);
  }
  #pragma unroll
  for (int j = 0; j < 16; ++j){
    float a = b3[j];
    #pragma unroll
    for (int i = 0; i < 8; ++i) a = fmaf(h2[i], w3[i*16+j], a);
    h3[j] = fmaxf(fmaf(a, sc3[j], sh3[j]), 0.f);
  }
  float4* o = (float4*)(WG + (size_t)idx*16);
  o[0] = make_float4(h3[0], h3[1], h3[2], h3[3]);
  o[1] = make_float4(h3[4], h3[5], h3[6], h3[7]);
  o[2] = make_float4(h3[8], h3[9], h3[10],h3[11]);
  o[3] = make_float4(h3[12],h3[13],h3[14],h3[15]);
}

// ---------------- K4a: pe via F-gather + einsum -> M chunk (wave = point, lane = c)
__global__ __launch_bounds__(256) void k4a2(const float* __restrict__ F,
                                            const int*   __restrict__ nei,
                                            const float* __restrict__ out2,
                                            const float* __restrict__ w_pe,
                                            const float* __restrict__ WG,
                                            const float* __restrict__ stats,
                                            float* __restrict__ M, int c0){
  __shared__ float  wn[4][192];
  __shared__ float4 wt[4][64];
  int tid = threadIdx.x, w = tid >> 6, lane = tid & 63;
  const float invc = 1.0f/1280000.0f;
  float sm = stats[lane]*invc, sq = stats[64+lane]*invc;
  float sc = rsqrtf(fmaxf(sq - sm*sm, 0.f) + 1e-5f);
  float sh = -sm*sc;
  float gw[12];
  #pragma unroll
  for (int i = 0; i < 12; ++i) gw[i] = w_pe[(64+i)*64 + lane];

  int p_local = blockIdx.x*4 + w;          // [0, CHUNK)
  int p = c0 + p_local;
  int base = (p >= NPN) ? NPN : 0;
  int nv = nei[p*16 + (lane & 15)];
  float xf[16];
  #pragma unroll
  for (int k = 0; k < 16; ++k){
    int row = base + __shfl(nv, k, 64);
    xf[k] = F[(size_t)row*64 + lane];      // coalesced 256B gather
  }
  const float* o2 = out2 + (size_t)p*192;  // 16 wni rows, contiguous
  wn[w][lane]     = o2[lane];
  wn[w][64+lane]  = o2[64+lane];
  wn[w][128+lane] = o2[128+lane];
  wt[w][lane] = ((const float4*)WG)[(size_t)p_local*64 + lane];

  float m[16];
  #pragma unroll
  for (int i = 0; i < 16; ++i) m[i] = 0.f;
  #pragma unroll 4
  for (int k = 0; k < 16; ++k){
    const float4* u = (const float4*)&wn[w][k*12];
    float4 u0 = u[0], u1 = u[1], u2 = u[2];
    float g = u0.x*gw[0];
    g = fmaf(u0.y, gw[1],  g); g = fmaf(u0.z, gw[2],  g); g = fmaf(u0.w, gw[3],  g);
    g = fmaf(u1.x, gw[4],  g); g = fmaf(u1.y, gw[5],  g); g = fmaf(u1.z, gw[6],  g);
    g = fmaf(u1.w, gw[7],  g); g = fmaf(u2.x, gw[8],  g); g = fmaf(u2.y, gw[9],  g);
    g = fmaf(u2.z, gw[10], g); g = fmaf(u2.w, gw[11], g);
    float pe = fmaxf(fmaf(xf[k] + g, sc, sh), 0.f);
    float4 w0 = wt[w][k*4+0], w1v = wt[w][k*4+1], w2v = wt[w][k*4+2], w3v = wt[w][k*4+3];
    m[0]  = fmaf(pe, w0.x,  m[0]);  m[1]  = fmaf(pe, w0.y,  m[1]);
    m[2]  = fmaf(pe, w0.z,  m[2]);  m[3]  = fmaf(pe, w0.w,  m[3]);
    m[4]  = fmaf(pe, w1v.x, m[4]);  m[5]  = fmaf(pe, w1v.y, m[5]);
    m[6]  = fmaf(pe, w1v.z, m[6]);  m[7]  = fmaf(pe, w1v.w, m[7]);
    m[8]  = fmaf(pe, w2v.x, m[8]);  m[9]  = fmaf(pe, w2v.y, m[9]);
    m[10] = fmaf(pe, w2v.z, m[10]); m[11] = fmaf(pe, w2v.w, m[11]);
    m[12] = fmaf(pe, w3v.x, m[12]); m[13] = fmaf(pe, w3v.y, m[13]);
    m[14] = fmaf(pe, w3v.z, m[14]); m[15] = fmaf(pe, w3v.w, m[15]);
  }
  float4* mo = (float4*)(M + (size_t)p_local*1024 + lane*16);
  mo[0] = make_float4(m[0], m[1], m[2], m[3]);
  mo[1] = make_float4(m[4], m[5], m[6], m[7]);
  mo[2] = make_float4(m[8], m[9], m[10],m[11]);
  mo[3] = make_float4(m[12],m[13],m[14],m[15]);
}

// ---------------- K4b: MFMA GEMM  (CHUNK x 1024)f32->bf16 @ wlT_bf16 -> LP chunk
// block: 32 rows x 128 cols, 4 waves; wave w owns cols [w*32, w*32+32)
__global__ __launch_bounds__(256) void k4b_mfma(const float* __restrict__ M,
                                                const short* __restrict__ wlT,
                                                const float* __restrict__ bl,
                                                float* __restrict__ LP, int c0){
  __shared__ short As[32][40];    // [m][k] bf16, pad 40 (80B stride: 2-way max)
  __shared__ short Bs[128][40];   // [n][k] bf16
  int tid = threadIdx.x, w = tid >> 6, lane = tid & 63;
  int pb = blockIdx.x*32;
  int wc = w*32;
  f32x4 acc[2][2];
  #pragma unroll
  for (int i = 0; i < 2; ++i)
    #pragma unroll
    for (int j = 0; j < 2; ++j) acc[i][j] = (f32x4){0.f,0.f,0.f,0.f};

  int arow = tid >> 3, akq = (tid & 7)*4;
  for (int k0 = 0; k0 < 1024; k0 += 32){
    float4 av = *(const float4*)&M[(size_t)(pb + arow)*1024 + k0 + akq];
    short4 a4;
    a4.x = (short)f2bf(av.x); a4.y = (short)f2bf(av.y);
    a4.z = (short)f2bf(av.z); a4.w = (short)f2bf(av.w);
    *(short4*)&As[arow][akq] = a4;
    #pragma unroll
    for (int e = 0; e < 2; ++e){
      int cid = tid + e*256;                  // 512 16B chunks
      int n = cid >> 2, sub = cid & 3;
      float4 bv = *(const float4*)(wlT + (size_t)n*1024 + k0 + sub*8);
      *(float4*)&Bs[n][sub*8] = bv;
    }
    __syncthreads();
    bf16x8 a0 = *(const bf16x8*)&As[(lane&15)     ][(lane>>4)*8];
    bf16x8 a1 = *(const bf16x8*)&As[16 + (lane&15)][(lane>>4)*8];
    bf16x8 b0 = *(const bf16x8*)&Bs[wc + (lane&15)     ][(lane>>4)*8];
    bf16x8 b1 = *(const bf16x8*)&Bs[wc + 16 + (lane&15)][(lane>>4)*8];
    acc[0][0] = __builtin_amdgcn_mfma_f32_16x16x32_bf16(a0, b0, acc[0][0], 0, 0, 0);
    acc[0][1] = __builtin_amdgcn_mfma_f32_16x16x32_bf16(a0, b1, acc[0][1], 0, 0, 0);
    acc[1][0] = __builtin_amdgcn_mfma_f32_16x16x32_bf16(a1, b0, acc[1][0], 0, 0, 0);
    acc[1][1] = __builtin_amdgcn_mfma_f32_16x16x32_bf16(a1, b1, acc[1][1], 0, 0, 0);
    __syncthreads();
  }
  float bc0 = bl[wc + (lane&15)];
  float bc1 = bl[wc + 16 + (lane&15)];
  #pragma unroll
  for (int mi = 0; mi < 2; ++mi){
    #pragma unroll
    for (int j = 0; j < 4; ++j){
      int rl = mi*16 + (lane>>4)*4 + j;            // C/D: col=lane&15, row=(lane>>4)*4+j
      size_t pr = (size_t)(c0 + pb + rl)*128;
      LP[pr + wc + (lane&15)]      = acc[mi][0][j] + bc0;
      LP[pr + wc + 16 + (lane&15)] = acc[mi][1][j] + bc1;
    }
  }
}

// ---------------- K4c: lin pre-act stats
__global__ __launch_bounds__(256) void k4c(const float* __restrict__ LP,
                                           float* __restrict__ stats){
  int tid = threadIdx.x; int ch = tid & 127; int half = tid >> 7;
  float s = 0.f, q = 0.f;
  for (int p = blockIdx.x*2 + half; p < NPTS; p += gridDim.x*2){
    float v = LP[(size_t)p*128 + ch]; s += v; q += v*v;
  }
  __shared__ float r[256];
  r[tid] = s; __syncthreads();
  if (tid < 128) atomicAdd(&stats[192 + tid], r[tid] + r[tid+128]);
  __syncthreads();
  r[tid] = q; __syncthreads();
  if (tid < 128) atomicAdd(&stats[320 + tid], r[tid] + r[tid+128]);
}

// ---------------- K5: apply lin BN + relu (in-place over LP region == out1)
__global__ __launch_bounds__(256) void k5(float* __restrict__ LP,
                                          const float* __restrict__ stats){
  __shared__ float sc[128], sh[128];
  int tid = threadIdx.x;
  if (tid < 128){
    const float invc = 1.0f/80000.0f;
    float s = stats[192+tid]*invc, q = stats[320+tid]*invc;
    float c = rsqrtf(fmaxf(q - s*s, 0.f) + 1e-5f);
    sc[tid] = c; sh[tid] = -s*c;
  }
  __syncthreads();
  for (int g4 = blockIdx.x*256 + tid; g4 < 2560000; g4 += gridDim.x*256){
    int cb = (g4 & 31) * 4;
    float4 v = ((const float4*)LP)[g4];
    float4 o;
    o.x = fmaxf(fmaf(v.x, sc[cb+0], sh[cb+0]), 0.f);
    o.y = fmaxf(fmaf(v.y, sc[cb+1], sh[cb+1]), 0.f);
    o.z = fmaxf(fmaf(v.z, sc[cb+2], sh[cb+2]), 0.f);
    o.w = fmaxf(fmaf(v.w, sc[cb+3], sh[cb+3]), 0.f);
    ((float4*)LP)[g4] = o;
  }
}

extern "C" void kernel_launch(void* const* d_in, const int* in_sizes, int n_in,
                              void* d_out, int out_size, void* d_ws, size_t ws_size,
                              hipStream_t stream){
  const float* xyz   = (const float*)d_in[0];
  const float* feats = (const float*)d_in[1];
  const float* nrm   = (const float*)d_in[2];
  const int*   nei   = (const int*)  d_in[3];
  const float* w_pe  = (const float*)d_in[4];
  const float* b_pe  = (const float*)d_in[5];
  const float* w1    = (const float*)d_in[6];
  const float* b1    = (const float*)d_in[7];
  const float* w2    = (const float*)d_in[8];
  const float* b2    = (const float*)d_in[9];
  const float* w3    = (const float*)d_in[10];
  const float* b3    = (const float*)d_in[11];
  const float* wl    = (const float*)d_in[12];
  const float* blin  = (const float*)d_in[13];

  float* out1 = (float*)d_out;             // new_feat (B,N,128); doubles as LP scratch
  float* out2 = out1 + 10240000;           // weightNetInput (B,N,K,12)

  // ws: stats 512 | F 5.12M (20.5MB) | WG 2.048M (8.2MB) | M 8.192M (32.8MB) | wlT 131072 shorts
  float* stats = (float*)d_ws;
  float* F     = stats + 512;
  float* WG    = F + (size_t)NPTS*64;
  float* M     = WG + (size_t)CHUNK*256;
  short* wlT   = (short*)(M + (size_t)CHUNK*1024);

  hipMemsetAsync(stats, 0, 512*sizeof(float), stream);
  kWT  <<<512,  256, 0, stream>>>(wl, wlT);
  kF   <<<640,  256, 0, stream>>>(feats, w_pe, b_pe, F);
  k_vi <<<625,  256, 0, stream>>>(xyz, nrm, nei, w1, b1, out2, stats);
  k_pe2<<<1280, 256, 0, stream>>>(F, nei, out2, w_pe, stats);
  k3a  <<<625,  256, 0, stream>>>(out2, w1, b1, w2, b2, stats);
  k3b  <<<625,  256, 0, stream>>>(out2, w1, b1, w2, b2, w3, b3, stats);
  for (int c = 0; c < NCHUNK; ++c){
    int c0 = c * CHUNK;
    k3c     <<<CHUNK*16/256, 256, 0, stream>>>(out2, w1, b1, w2, b2, w3, b3, stats, WG, c0);
    k4a2    <<<CHUNK/4,      256, 0, stream>>>(F, nei, out2, w_pe, WG, stats, M, c0);
    k4b_mfma<<<CHUNK/32,     256, 0, stream>>>(M, wlT, blin, out1, c0);
  }
  k4c<<<512, 256, 0, stream>>>(out1, stats);
  k5 <<<1280, 256, 0, stream>>>(out1, stats);
}

// Round 8
// 666.427 us; speedup vs baseline: 2.0275x; 1.4185x over previous
//
#include <hip/hip_runtime.h>
#include <hip/hip_bf16.h>

#define NPK   1280000   // B*N*K
#define NPTS  80000     // B*N
#define NK    640000    // N*K
#define NPN   40000     // N

// stats layout in ws (floats):
// [0,64) pe_sum [64,128) pe_sq | [128,136) h1_sum [136,144) h1_sq
// [144,152) h2_sum [152,160) h2_sq | [160,176) h3_sum [176,192) h3_sq
// [192,320) lin_sum [320,448) lin_sq

typedef __attribute__((ext_vector_type(8))) short bf16x8;
typedef __attribute__((ext_vector_type(4))) float f32x4;

__device__ inline unsigned short f2bf(float f){       // RNE f32->bf16
  union { float f; unsigned u; } v; v.f = f;
  unsigned r = v.u + 0x7FFFu + ((v.u >> 16) & 1u);
  return (unsigned short)(r >> 16);
}
__device__ inline float bf2f(unsigned short u){
  union { unsigned u; float f; } v; v.u = ((unsigned)u) << 16; return v.f;
}

__device__ inline float wred(float v){
  #pragma unroll
  for (int m = 32; m; m >>= 1) v += __shfl_xor(v, m, 64);
  return v;
}

// ---------------- kP: pack xyz+nrm -> P[row][8] = {x,y,z,0, nx,ny,nz,0}
__global__ __launch_bounds__(256) void kP(const float* __restrict__ xyz,
                                          const float* __restrict__ nrm,
                                          float* __restrict__ P){
  int r = blockIdx.x*256 + threadIdx.x;
  if (r >= NPTS) return;
  float4 a = make_float4(xyz[r*3], xyz[r*3+1], xyz[r*3+2], 0.f);
  float4 b = make_float4(nrm[r*3], nrm[r*3+1], nrm[r*3+2], 0.f);
  ((float4*)P)[r*2]   = a;
  ((float4*)P)[r*2+1] = b;
}

// ---------------- kWT: w_lin -> transposed bf16 copy wlT[n][k]
__global__ __launch_bounds__(256) void kWT(const float* __restrict__ wl,
                                           unsigned short* __restrict__ wlT){
  int idx = blockIdx.x*256 + threadIdx.x;          // 512*256 = 131072
  float v = wl[idx];
  int k = idx >> 7, n = idx & 127;
  wlT[(size_t)n*1024 + k] = f2bf(v);
}

// ---------------- kF: F = feats @ w_pe[:64,:] + b_pe   (80000 x 64)
__global__ __launch_bounds__(256, 2) void kF(const float* __restrict__ feats,
                                             const float* __restrict__ w_pe,
                                             const float* __restrict__ b_pe,
                                             float* __restrict__ F){
  __shared__ float af[4][64];
  int tid = threadIdx.x, w = tid >> 6, lane = tid & 63;
  float wf[64];
  #pragma unroll
  for (int i = 0; i < 64; ++i) wf[i] = w_pe[i*64 + lane];
  float bp = b_pe[lane];
  int wid = blockIdx.x*4 + w;
  for (int r = wid; r < NPTS; r += 2560){
    af[w][lane] = feats[(size_t)r*64 + lane];
    const float4* ar = (const float4*)&af[w][0];
    float acc = bp;
    #pragma unroll
    for (int i = 0; i < 16; ++i){
      float4 a4 = ar[i];
      acc = fmaf(a4.x, wf[4*i+0], acc);
      acc = fmaf(a4.y, wf[4*i+1], acc);
      acc = fmaf(a4.z, wf[4*i+2], acc);
      acc = fmaf(a4.w, wf[4*i+3], acc);
    }
    F[(size_t)r*64 + lane] = acc;
  }
}

// ---------------- K1: VI transform -> out2, h1 pre-act stats (reads packed P)
__global__ __launch_bounds__(256) void k_vi(const float* __restrict__ P,
                                            const int*   __restrict__ nei,
                                            const float* __restrict__ w1,
                                            const float* __restrict__ b1,
                                            float* __restrict__ out2,
                                            float* __restrict__ stats){
  int tid = threadIdx.x;
  float s[8] = {0,0,0,0,0,0,0,0}, q[8] = {0,0,0,0,0,0,0,0};
  #pragma unroll 1
  for (int it = 0; it < 8; ++it){
    int g = blockIdx.x*256 + tid + it*160000;       // 625*256*8 == NPK
    int b  = g / NK;
    int nk = g - b*NK;
    int n  = nk >> 4;
    int pr = b*NPN + n;
    int jr = b*NPN + nei[g];
    float4 c0 = ((const float4*)P)[pr*2], c1 = ((const float4*)P)[pr*2+1];
    float4 j0 = ((const float4*)P)[jr*2], j1 = ((const float4*)P)[jr*2+1];
    float nx = c1.x, ny = c1.y, nz = c1.z;
    float lx = j0.x - c0.x, ly = j0.y - c0.y, lz = j0.z - c0.z;
    float gx = j1.x, gy = j1.y, gz = j1.z;
    float t9 = sqrtf(lx*lx + ly*ly + lz*lz);
    float ir = 1.0f / fmaxf(t9, 1e-12f);
    float rx = lx*ir, ry = ly*ir, rz = lz*ir;
    float t2 = nx*rx + ny*ry + nz*rz;
    float vx = nx - t2*rx, vy = ny - t2*ry, vz = nz - t2*rz;
    float vn = sqrtf(vx*vx + vy*vy + vz*vz);
    float iv = 1.0f / fmaxf(vn, 1e-12f);
    vx *= iv; vy *= iv; vz *= iv;
    float wx = ry*vz - rz*vy, wy = rz*vx - rx*vz, wz = rx*vy - ry*vx;
    float wn = sqrtf(wx*wx + wy*wy + wz*wz);
    float iw = 1.0f / fmaxf(wn, 1e-12f);
    wx *= iw; wy *= iw; wz *= iw;
    float t1 = gx*nx + gy*ny + gz*nz;
    float t3 = rx*gx + ry*gy + rz*gz;
    float t4 = lx*nx + ly*ny + lz*nz;
    float t6 = gx*vx + gy*vy + gz*vz;
    float t7 = gx*wx + gy*wy + gz*wz;
    float ccx = gy*nz - gz*ny, ccy = gz*nx - gx*nz, ccz = gx*ny - gy*nx;
    float t8 = lx*ccx + ly*ccy + lz*ccz;
    float wni[12] = {t1,t2,t3,t4,t3,t6,t7,t8,t9,lx,ly,lz};   // t5 == t3
    float4* o = (float4*)(out2 + (size_t)g*12);
    o[0] = make_float4(t1,t2,t3,t4);
    o[1] = make_float4(t3,t6,t7,t8);
    o[2] = make_float4(t9,lx,ly,lz);
    #pragma unroll
    for (int jj = 0; jj < 8; ++jj){
      float a = b1[jj];
      #pragma unroll
      for (int i = 0; i < 12; ++i) a = fmaf(wni[i], w1[i*8 + jj], a);
      s[jj] += a; q[jj] += a*a;
    }
  }
  __shared__ float red[4][16];
  int lane = tid & 63, wv = tid >> 6;
  float st[16];
  #pragma unroll
  for (int i = 0; i < 8; ++i){ st[i] = s[i]; st[8+i] = q[i]; }
  #pragma unroll
  for (int i = 0; i < 16; ++i) st[i] = wred(st[i]);
  if (lane == 0){
    #pragma unroll
    for (int i = 0; i < 16; ++i) red[wv][i] = st[i];
  }
  __syncthreads();
  if (tid < 16)
    atomicAdd(&stats[128 + tid], red[0][tid] + red[1][tid] + red[2][tid] + red[3][tid]);
}

// ---------------- K2: pe pre-act stats via F-gather (lane = channel)
__global__ __launch_bounds__(256) void k_pe2(const float* __restrict__ F,
                                             const int*   __restrict__ nei,
                                             const float* __restrict__ out2,
                                             const float* __restrict__ w_pe,
                                             float* __restrict__ stats){
  int tid = threadIdx.x, lane = tid & 63;
  float gw[12];
  #pragma unroll
  for (int i = 0; i < 12; ++i) gw[i] = w_pe[(64+i)*64 + lane];
  float s = 0.f, q = 0.f;
  int wid = blockIdx.x*4 + (tid >> 6);
  #pragma unroll 4
  for (int pk = wid; pk < NPK; pk += 8192){
    int row = (pk >= NK ? NPN : 0) + nei[pk];
    float xv = F[(size_t)row*64 + lane];            // coalesced 256B gather
    const float4* wp = (const float4*)(out2 + (size_t)pk*12);
    float4 u0 = wp[0], u1 = wp[1], u2 = wp[2];      // wave-uniform broadcast
    float g = u0.x*gw[0];
    g = fmaf(u0.y, gw[1],  g); g = fmaf(u0.z, gw[2],  g); g = fmaf(u0.w, gw[3],  g);
    g = fmaf(u1.x, gw[4],  g); g = fmaf(u1.y, gw[5],  g); g = fmaf(u1.z, gw[6],  g);
    g = fmaf(u1.w, gw[7],  g); g = fmaf(u2.x, gw[8],  g); g = fmaf(u2.y, gw[9],  g);
    g = fmaf(u2.z, gw[10], g); g = fmaf(u2.w, gw[11], g);
    float x = xv + g;
    s += x; q += x*x;
  }
  __shared__ float r[256];
  r[tid] = s; __syncthreads();
  if (tid < 64) atomicAdd(&stats[tid],      r[tid] + r[tid+64] + r[tid+128] + r[tid+192]);
  __syncthreads();
  r[tid] = q; __syncthreads();
  if (tid < 64) atomicAdd(&stats[64 + tid], r[tid] + r[tid+64] + r[tid+128] + r[tid+192]);
}

// ---------------- K3a: h2 pre-act stats
__global__ __launch_bounds__(256) void k3a(const float* __restrict__ out2,
                                           const float* __restrict__ w1, const float* __restrict__ b1,
                                           const float* __restrict__ w2, const float* __restrict__ b2,
                                           float* __restrict__ stats){
  int tid = threadIdx.x;
  const float invc = 1.0f/1280000.0f;
  float sc1[8], sh1[8];
  #pragma unroll
  for (int j = 0; j < 8; ++j){
    float m = stats[128+j]*invc, v = stats[136+j]*invc - m*m;
    float c = rsqrtf(fmaxf(v, 0.f) + 1e-5f); sc1[j] = c; sh1[j] = -m*c;
  }
  float s[8] = {0,0,0,0,0,0,0,0}, q[8] = {0,0,0,0,0,0,0,0};
  #pragma unroll 1
  for (int it = 0; it < 8; ++it){
    int g = blockIdx.x*256 + tid + it*160000;
    const float4* wp = (const float4*)(out2 + (size_t)g*12);
    float4 a0 = wp[0], a1 = wp[1], a2 = wp[2];
    float wni[12] = {a0.x,a0.y,a0.z,a0.w,a1.x,a1.y,a1.z,a1.w,a2.x,a2.y,a2.z,a2.w};
    float h1[8];
    #pragma unroll
    for (int j = 0; j < 8; ++j){
      float a = b1[j];
      #pragma unroll
      for (int i = 0; i < 12; ++i) a = fmaf(wni[i], w1[i*8+j], a);
      h1[j] = fmaxf(fmaf(a, sc1[j], sh1[j]), 0.f);
    }
    #pragma unroll
    for (int j = 0; j < 8; ++j){
      float a = b2[j];
      #pragma unroll
      for (int i = 0; i < 8; ++i) a = fmaf(h1[i], w2[i*8+j], a);
      s[j] += a; q[j] += a*a;
    }
  }
  __shared__ float red[4][16];
  int lane = tid & 63, wv = tid >> 6;
  float st[16];
  #pragma unroll
  for (int i = 0; i < 8; ++i){ st[i] = s[i]; st[8+i] = q[i]; }
  #pragma unroll
  for (int i = 0; i < 16; ++i) st[i] = wred(st[i]);
  if (lane == 0){
    #pragma unroll
    for (int i = 0; i < 16; ++i) red[wv][i] = st[i];
  }
  __syncthreads();
  if (tid < 16)
    atomicAdd(&stats[144 + tid], red[0][tid] + red[1][tid] + red[2][tid] + red[3][tid]);
}

// ---------------- K3b: h3 pre-act stats
__global__ __launch_bounds__(256) void k3b(const float* __restrict__ out2,
                                           const float* __restrict__ w1, const float* __restrict__ b1,
                                           const float* __restrict__ w2, const float* __restrict__ b2,
                                           const float* __restrict__ w3, const float* __restrict__ b3,
                                           float* __restrict__ stats){
  int tid = threadIdx.x;
  const float invc = 1.0f/1280000.0f;
  float sc1[8], sh1[8], sc2[8], sh2[8];
  #pragma unroll
  for (int j = 0; j < 8; ++j){
    float m = stats[128+j]*invc, v = stats[136+j]*invc - m*m;
    float c = rsqrtf(fmaxf(v, 0.f) + 1e-5f); sc1[j] = c; sh1[j] = -m*c;
    m = stats[144+j]*invc; v = stats[152+j]*invc - m*m;
    c = rsqrtf(fmaxf(v, 0.f) + 1e-5f); sc2[j] = c; sh2[j] = -m*c;
  }
  float s[16], q[16];
  #pragma unroll
  for (int j = 0; j < 16; ++j){ s[j] = 0.f; q[j] = 0.f; }
  #pragma unroll 1
  for (int it = 0; it < 8; ++it){
    int g = blockIdx.x*256 + tid + it*160000;
    const float4* wp = (const float4*)(out2 + (size_t)g*12);
    float4 a0 = wp[0], a1 = wp[1], a2 = wp[2];
    float wni[12] = {a0.x,a0.y,a0.z,a0.w,a1.x,a1.y,a1.z,a1.w,a2.x,a2.y,a2.z,a2.w};
    float h1[8], h2[8];
    #pragma unroll
    for (int j = 0; j < 8; ++j){
      float a = b1[j];
      #pragma unroll
      for (int i = 0; i < 12; ++i) a = fmaf(wni[i], w1[i*8+j], a);
      h1[j] = fmaxf(fmaf(a, sc1[j], sh1[j]), 0.f);
    }
    #pragma unroll
    for (int j = 0; j < 8; ++j){
      float a = b2[j];
      #pragma unroll
      for (int i = 0; i < 8; ++i) a = fmaf(h1[i], w2[i*8+j], a);
      h2[j] = fmaxf(fmaf(a, sc2[j], sh2[j]), 0.f);
    }
    #pragma unroll
    for (int j = 0; j < 16; ++j){
      float a = b3[j];
      #pragma unroll
      for (int i = 0; i < 8; ++i) a = fmaf(h2[i], w3[i*16+j], a);
      s[j] += a; q[j] += a*a;
    }
  }
  __shared__ float red[4][32];
  int lane = tid & 63, wv = tid >> 6;
  float st[32];
  #pragma unroll
  for (int i = 0; i < 16; ++i){ st[i] = s[i]; st[16+i] = q[i]; }
  #pragma unroll
  for (int i = 0; i < 32; ++i) st[i] = wred(st[i]);
  if (lane == 0){
    #pragma unroll
    for (int i = 0; i < 32; ++i) red[wv][i] = st[i];
  }
  __syncthreads();
  if (tid < 32)
    atomicAdd(&stats[160 + tid], red[0][tid] + red[1][tid] + red[2][tid] + red[3][tid]);
}

// ---------------- K3c: full MLP chain -> WGb (bf16, all points, one launch)
__global__ __launch_bounds__(256) void k3c(const float* __restrict__ out2,
                                           const float* __restrict__ w1, const float* __restrict__ b1,
                                           const float* __restrict__ w2, const float* __restrict__ b2,
                                           const float* __restrict__ w3, const float* __restrict__ b3,
                                           const float* __restrict__ stats,
                                           unsigned short* __restrict__ WGb){
  int idx = blockIdx.x*256 + threadIdx.x;        // [0, NPK)
  const float invc = 1.0f/1280000.0f;
  float sc1[8], sh1[8], sc2[8], sh2[8], sc3[16], sh3[16];
  #pragma unroll
  for (int j = 0; j < 8; ++j){
    float m = stats[128+j]*invc, v = stats[136+j]*invc - m*m;
    float c = rsqrtf(fmaxf(v, 0.f) + 1e-5f); sc1[j] = c; sh1[j] = -m*c;
    m = stats[144+j]*invc; v = stats[152+j]*invc - m*m;
    c = rsqrtf(fmaxf(v, 0.f) + 1e-5f); sc2[j] = c; sh2[j] = -m*c;
  }
  #pragma unroll
  for (int j = 0; j < 16; ++j){
    float m = stats[160+j]*invc, v = stats[176+j]*invc - m*m;
    float c = rsqrtf(fmaxf(v, 0.f) + 1e-5f); sc3[j] = c; sh3[j] = -m*c;
  }
  const float4* wp = (const float4*)(out2 + (size_t)idx*12);
  float4 a0 = wp[0], a1 = wp[1], a2 = wp[2];
  float wni[12] = {a0.x,a0.y,a0.z,a0.w,a1.x,a1.y,a1.z,a1.w,a2.x,a2.y,a2.z,a2.w};
  float h1[8], h2[8], h3[16];
  #pragma unroll
  for (int j = 0; j < 8; ++j){
    float a = b1[j];
    #pragma unroll
    for (int i = 0; i < 12; ++i) a = fmaf(wni[i], w1[i*8+j], a);
    h1[j] = fmaxf(fmaf(a, sc1[j], sh1[j]), 0.f);
  }
  #pragma unroll
  for (int j = 0; j < 8; ++j){
    float a = b2[j];
    #pragma unroll
    for (int i = 0; i < 8; ++i) a = fmaf(h1[i], w2[i*8+j], a);
    h2[j] = fmaxf(fmaf(a, sc2[j], sh2[j]), 0.f);
  }
  #pragma unroll
  for (int j = 0; j < 16; ++j){
    float a = b3[j];
    #pragma unroll
    for (int i = 0; i < 8; ++i) a = fmaf(h2[i], w3[i*16+j], a);
    h3[j] = fmaxf(fmaf(a, sc3[j], sh3[j]), 0.f);
  }
  unsigned pk2[8];
  #pragma unroll
  for (int i = 0; i < 8; ++i)
    pk2[i] = (unsigned)f2bf(h3[2*i]) | ((unsigned)f2bf(h3[2*i+1]) << 16);
  uint4* o = (uint4*)(WGb + (size_t)idx*16);
  o[0] = make_uint4(pk2[0], pk2[1], pk2[2], pk2[3]);
  o[1] = make_uint4(pk2[4], pk2[5], pk2[6], pk2[7]);
}

// ---------------- K4f: fused einsum -> LDS bf16 M-tile -> MFMA GEMM -> LP
// block = 32 points, 4 waves. Wave w: einsum for points w*8..w*8+7 (lane = pe channel),
// then GEMM cols [w*32, w*32+32). As XOR-swizzled (row stride 2048B would be 16-way).
__global__ __launch_bounds__(256, 2) void k4f(const float* __restrict__ F,
                                              const int*   __restrict__ nei,
                                              const float* __restrict__ out2,
                                              const float* __restrict__ w_pe,
                                              const unsigned short* __restrict__ WGb,
                                              const float* __restrict__ stats,
                                              const unsigned short* __restrict__ wlT,
                                              const float* __restrict__ blin,
                                              float* __restrict__ LP){
  __shared__ short  As[32][1024];   // 64KB bf16 M-tile, XOR-swizzled
  __shared__ short  Bs[128][32];    // 8KB  bf16 wlT K-slab, XOR-swizzled
  __shared__ float4 wt[4][64];      // 4KB  wgt (f32) per wave's current point
  __shared__ float  wn[4][192];     // 3KB  wni rows per wave's current point
  int tid = threadIdx.x, w = tid >> 6, lane = tid & 63;
  char* asb = (char*)&As[0][0];
  char* bsb = (char*)&Bs[0][0];
  const float invc = 1.0f/1280000.0f;
  float sm = stats[lane]*invc, sq = stats[64+lane]*invc;
  float sc = rsqrtf(fmaxf(sq - sm*sm, 0.f) + 1e-5f);
  float sh = -sm*sc;
  float gw[12];
  #pragma unroll
  for (int i = 0; i < 12; ++i) gw[i] = w_pe[(64+i)*64 + lane];
  int p_base = blockIdx.x*32;

  // ---- einsum phase: 8 points per wave ----
  #pragma unroll 1
  for (int pi = 0; pi < 8; ++pi){
    int row = w*8 + pi;
    int p = p_base + row;
    int base = (p >= NPN) ? NPN : 0;
    int nv = nei[p*16 + (lane & 15)];
    float xf[16];
    #pragma unroll
    for (int k = 0; k < 16; ++k){
      int r = base + __shfl(nv, k, 64);
      xf[k] = F[(size_t)r*64 + lane];              // coalesced 256B gather
    }
    const float* o2 = out2 + (size_t)p*192;
    wn[w][lane]     = o2[lane];
    wn[w][64+lane]  = o2[64+lane];
    wn[w][128+lane] = o2[128+lane];
    ushort4 wv = *(const ushort4*)(WGb + (size_t)p*256 + lane*4);
    wt[w][lane] = make_float4(bf2f(wv.x), bf2f(wv.y), bf2f(wv.z), bf2f(wv.w));
    float m[16];
    #pragma unroll
    for (int i = 0; i < 16; ++i) m[i] = 0.f;
    #pragma unroll 4
    for (int k = 0; k < 16; ++k){
      const float4* u = (const float4*)&wn[w][k*12];
      float4 u0 = u[0], u1 = u[1], u2 = u[2];
      float g = u0.x*gw[0];
      g = fmaf(u0.y, gw[1],  g); g = fmaf(u0.z, gw[2],  g); g = fmaf(u0.w, gw[3],  g);
      g = fmaf(u1.x, gw[4],  g); g = fmaf(u1.y, gw[5],  g); g = fmaf(u1.z, gw[6],  g);
      g = fmaf(u1.w, gw[7],  g); g = fmaf(u2.x, gw[8],  g); g = fmaf(u2.y, gw[9],  g);
      g = fmaf(u2.z, gw[10], g); g = fmaf(u2.w, gw[11], g);
      float pe = fmaxf(fmaf(xf[k] + g, sc, sh), 0.f);
      float4 w0 = wt[w][k*4+0], w1v = wt[w][k*4+1], w2v = wt[w][k*4+2], w3v = wt[w][k*4+3];
      m[0]  = fmaf(pe, w0.x,  m[0]);  m[1]  = fmaf(pe, w0.y,  m[1]);
      m[2]  = fmaf(pe, w0.z,  m[2]);  m[3]  = fmaf(pe, w0.w,  m[3]);
      m[4]  = fmaf(pe, w1v.x, m[4]);  m[5]  = fmaf(pe, w1v.y, m[5]);
      m[6]  = fmaf(pe, w1v.z, m[6]);  m[7]  = fmaf(pe, w1v.w, m[7]);
      m[8]  = fmaf(pe, w2v.x, m[8]);  m[9]  = fmaf(pe, w2v.y, m[9]);
      m[10] = fmaf(pe, w2v.z, m[10]); m[11] = fmaf(pe, w2v.w, m[11]);
      m[12] = fmaf(pe, w3v.x, m[12]); m[13] = fmaf(pe, w3v.y, m[13]);
      m[14] = fmaf(pe, w3v.z, m[14]); m[15] = fmaf(pe, w3v.w, m[15]);
    }
    bf16x8 lo, hi;
    #pragma unroll
    for (int i = 0; i < 8; ++i){ lo[i] = (short)f2bf(m[i]); hi[i] = (short)f2bf(m[8+i]); }
    unsigned xr = (unsigned)((row & 7) << 4);
    unsigned b0 = (unsigned)(row*2048 + lane*32);
    *(bf16x8*)(asb + ( b0        ^ xr)) = lo;
    *(bf16x8*)(asb + ((b0 + 16)  ^ xr)) = hi;
  }
  __syncthreads();

  // ---- GEMM phase: LP[32x128] = As[32x1024]_bf16 @ wlT^T ----
  f32x4 acc[2][2];
  #pragma unroll
  for (int i = 0; i < 2; ++i)
    #pragma unroll
    for (int j = 0; j < 2; ++j) acc[i][j] = (f32x4){0.f,0.f,0.f,0.f};
  int r15 = lane & 15, q = lane >> 4;
  unsigned xrA = (unsigned)((r15 & 7) << 4);       // (16+r15)&7 == r15&7
  #pragma unroll 1
  for (int ks = 0; ks < 32; ++ks){
    {   // stage Bs[128][32] from wlT (L2-hot, 256KB total)
      int n = tid >> 1, kh = tid & 1;
      const unsigned short* src = wlT + (size_t)n*1024 + ks*32 + kh*16;
      bf16x8 v0 = *(const bf16x8*)(src);
      bf16x8 v1 = *(const bf16x8*)(src + 8);
      unsigned bb = (unsigned)(n*64 + kh*32);
      unsigned xb = (unsigned)((n & 3) << 4);
      *(bf16x8*)(bsb + ( bb        ^ xb)) = v0;
      *(bf16x8*)(bsb + ((bb + 16)  ^ xb)) = v1;
    }
    __syncthreads();
    unsigned ka = (unsigned)(ks*64 + q*16);
    bf16x8 a0 = *(const bf16x8*)(asb + ((unsigned)( r15     *2048 + ka) ^ xrA));
    bf16x8 a1 = *(const bf16x8*)(asb + ((unsigned)((16+r15)*2048 + ka) ^ xrA));
    int n0 = w*32 + r15, n1 = n0 + 16;
    bf16x8 b0 = *(const bf16x8*)(bsb + ((unsigned)(n0*64 + q*16) ^ (unsigned)((n0 & 3) << 4)));
    bf16x8 b1 = *(const bf16x8*)(bsb + ((unsigned)(n1*64 + q*16) ^ (unsigned)((n1 & 3) << 4)));
    acc[0][0] = __builtin_amdgcn_mfma_f32_16x16x32_bf16(a0, b0, acc[0][0], 0, 0, 0);
    acc[0][1] = __builtin_amdgcn_mfma_f32_16x16x32_bf16(a0, b1, acc[0][1], 0, 0, 0);
    acc[1][0] = __builtin_amdgcn_mfma_f32_16x16x32_bf16(a1, b0, acc[1][0], 0, 0, 0);
    acc[1][1] = __builtin_amdgcn_mfma_f32_16x16x32_bf16(a1, b1, acc[1][1], 0, 0, 0);
    __syncthreads();
  }
  float bc0 = blin[w*32 + r15], bc1 = blin[w*32 + 16 + r15];
  #pragma unroll
  for (int mi = 0; mi < 2; ++mi){
    #pragma unroll
    for (int j = 0; j < 4; ++j){
      int prow = p_base + mi*16 + q*4 + j;         // C/D: col=lane&15, row=(lane>>4)*4+j
      LP[(size_t)prow*128 + w*32 + r15]      = acc[mi][0][j] + bc0;
      LP[(size_t)prow*128 + w*32 + 16 + r15] = acc[mi][1][j] + bc1;
    }
  }
}

// ---------------- K4c: lin pre-act stats
__global__ __launch_bounds__(256) void k4c(const float* __restrict__ LP,
                                           float* __restrict__ stats){
  int tid = threadIdx.x; int ch = tid & 127; int half = tid >> 7;
  float s = 0.f, q = 0.f;
  for (int p = blockIdx.x*2 + half; p < NPTS; p += gridDim.x*2){
    float v = LP[(size_t)p*128 + ch]; s += v; q += v*v;
  }
  __shared__ float r[256];
  r[tid] = s; __syncthreads();
  if (tid < 128) atomicAdd(&stats[192 + tid], r[tid] + r[tid+128]);
  __syncthreads();
  r[tid] = q; __syncthreads();
  if (tid < 128) atomicAdd(&stats[320 + tid], r[tid] + r[tid+128]);
}

// ---------------- K5: apply lin BN + relu (in-place over LP region == out1)
__global__ __launch_bounds__(256) void k5(float* __restrict__ LP,
                                          const float* __restrict__ stats){
  __shared__ float sc[128], sh[128];
  int tid = threadIdx.x;
  if (tid < 128){
    const float invc = 1.0f/80000.0f;
    float s = stats[192+tid]*invc, q = stats[320+tid]*invc;
    float c = rsqrtf(fmaxf(q - s*s, 0.f) + 1e-5f);
    sc[tid] = c; sh[tid] = -s*c;
  }
  __syncthreads();
  for (int g4 = blockIdx.x*256 + tid; g4 < 2560000; g4 += gridDim.x*256){
    int cb = (g4 & 31) * 4;
    float4 v = ((const float4*)LP)[g4];
    float4 o;
    o.x = fmaxf(fmaf(v.x, sc[cb+0], sh[cb+0]), 0.f);
    o.y = fmaxf(fmaf(v.y, sc[cb+1], sh[cb+1]), 0.f);
    o.z = fmaxf(fmaf(v.z, sc[cb+2], sh[cb+2]), 0.f);
    o.w = fmaxf(fmaf(v.w, sc[cb+3], sh[cb+3]), 0.f);
    ((float4*)LP)[g4] = o;
  }
}

extern "C" void kernel_launch(void* const* d_in, const int* in_sizes, int n_in,
                              void* d_out, int out_size, void* d_ws, size_t ws_size,
                              hipStream_t stream){
  const float* xyz   = (const float*)d_in[0];
  const float* feats = (const float*)d_in[1];
  const float* nrm   = (const float*)d_in[2];
  const int*   nei   = (const int*)  d_in[3];
  const float* w_pe  = (const float*)d_in[4];
  const float* b_pe  = (const float*)d_in[5];
  const float* w1    = (const float*)d_in[6];
  const float* b1    = (const float*)d_in[7];
  const float* w2    = (const float*)d_in[8];
  const float* b2    = (const float*)d_in[9];
  const float* w3    = (const float*)d_in[10];
  const float* b3    = (const float*)d_in[11];
  const float* wl    = (const float*)d_in[12];
  const float* blin  = (const float*)d_in[13];

  float* out1 = (float*)d_out;             // new_feat (B,N,128); doubles as LP scratch
  float* out2 = out1 + 10240000;           // weightNetInput (B,N,K,12)

  // ws: stats 512f | F 5.12Mf (20.5MB) | P 640Kf (2.56MB) | wlT 131072 u16 | WGb 20.48M u16 (41MB)
  float* stats        = (float*)d_ws;
  float* F            = stats + 512;
  float* P            = F + (size_t)NPTS*64;
  unsigned short* wlT = (unsigned short*)(P + (size_t)NPTS*8);
  unsigned short* WGb = wlT + 131072;

  hipMemsetAsync(stats, 0, 512*sizeof(float), stream);
  kP   <<<(NPTS+255)/256, 256, 0, stream>>>(xyz, nrm, P);
  kWT  <<<512,  256, 0, stream>>>(wl, wlT);
  kF   <<<640,  256, 0, stream>>>(feats, w_pe, b_pe, F);
  k_vi <<<625,  256, 0, stream>>>(P, nei, w1, b1, out2, stats);
  k_pe2<<<2048, 256, 0, stream>>>(F, nei, out2, w_pe, stats);
  k3a  <<<625,  256, 0, stream>>>(out2, w1, b1, w2, b2, stats);
  k3b  <<<625,  256, 0, stream>>>(out2, w1, b1, w2, b2, w3, b3, stats);
  k3c  <<<5000, 256, 0, stream>>>(out2, w1, b1, w2, b2, w3, b3, stats, WGb);
  k4f  <<<2500, 256, 0, stream>>>(F, nei, out2, w_pe, WGb, stats, wlT, blin, out1);
  k4c  <<<512,  256, 0, stream>>>(out1, stats);
  k5   <<<1280, 256, 0, stream>>>(out1, stats);
}